// Round 10
// baseline (218.699 us; speedup 1.0000x reference)
//
#include <hip/hip_runtime.h>

// ---------------- helpers ----------------

typedef __bf16 bf16x8 __attribute__((ext_vector_type(8)));
typedef float  f32x4  __attribute__((ext_vector_type(4)));

__device__ __forceinline__ unsigned short f2bf(float x) {
    unsigned int u = __builtin_bit_cast(unsigned int, x);
    u = (u + 0x7fffu + ((u >> 16) & 1u)) >> 16;
    return (unsigned short)u;
}

__device__ __forceinline__ void gl2lds16(const unsigned short* g, unsigned short* l) {
    __builtin_amdgcn_global_load_lds(
        (const __attribute__((address_space(1))) unsigned int*)g,
        (__attribute__((address_space(3))) unsigned int*)l,
        16, 0, 0);
}

__device__ __forceinline__ float sigf(float x) {
    return __builtin_amdgcn_rcpf(1.f + __expf(-x));
}
__device__ __forceinline__ float tanh_fast(float x) {
    return 2.f * __builtin_amdgcn_rcpf(1.f + __expf(-2.f * x)) - 1.f;
}

// ---------------- fused conversion kernel ----------------
// blocks [0,16384): activations -> bf16 A [4096][4096]
// blocks [16384,32768): weights -> bf16 B^T with gate-interleave permutation.
//   For the 4-wave 256^2 GEMM (wave-tile 128x128, 8 ni-frags), lane lr of wave wn
//   holds gates a,i,f,o of units u0 = bc*64 + wn*32 + lr (frags ni=0..3) and
//   u1 = u0+16 (frags ni=4..7):
//   p(u,g) = (u>>6)*256 + ((u>>5)&1)*128 + (g + ((u>>4)&1)*4)*16 + (u&15)

__global__ void convert_AB(const float* __restrict__ A0, const float* __restrict__ A1,
                           const float* __restrict__ A2, const float* __restrict__ A3,
                           const float* __restrict__ Wb, const float* __restrict__ W1,
                           const float* __restrict__ W2, const float* __restrict__ Wl,
                           unsigned short* __restrict__ Abf,
                           unsigned short* __restrict__ Bt) {
    __shared__ float t[32][33];
    if (blockIdx.x < 16384) {
        int idx = blockIdx.x * 256 + threadIdx.x;
        int e0  = idx * 4;
        int b   = e0 >> 12;
        int k   = e0 & 4095;
        const float* S = (k < 1024) ? A0 : (k < 2048) ? A1 : (k < 3072) ? A2 : A3;
        int col = k & 1023;
        const float4 v = *reinterpret_cast<const float4*>(S + (size_t)b * 1024 + col);
        ushort4 o;
        o.x = f2bf(v.x); o.y = f2bf(v.y); o.z = f2bf(v.z); o.w = f2bf(v.w);
        *reinterpret_cast<ushort4*>(Abf + (size_t)b * 4096 + k) = o;
    } else {
        int tile = blockIdx.x - 16384;    // 128 j-tiles x 128 k-tiles
        int jt = tile & 127, kt = tile >> 7;
        int j0 = jt * 32, k0 = kt * 32;
        int ksel = k0 >> 10;
        const float* S = (ksel == 0) ? Wb : (ksel == 1) ? W1 : (ksel == 2) ? W2 : Wl;
        int kloc = k0 & 1023;
        int tx = threadIdx.x & 31, ty = threadIdx.x >> 5;
#pragma unroll
        for (int i = 0; i < 4; ++i) {
            int r = ty + i * 8;
            t[r][tx] = S[(size_t)(kloc + r) * 4096 + j0 + tx];
        }
        __syncthreads();
        int g = j0 >> 10;
        int nbase = j0 & 1023;
#pragma unroll
        for (int i = 0; i < 4; ++i) {
            int jj = ty + i * 8;
            int u  = nbase + jj;
            int p  = (u >> 6) * 256 + ((u >> 5) & 1) * 128 + (g + ((u >> 4) & 1) * 4) * 16 + (u & 15);
            Bt[(size_t)p * 4096 + k0 + tx] = f2bf(t[tx][jj]);
        }
    }
}

// ---------------- 256x256 GEMM, 4 waves, wave-tile 128x128 + fused LSTM ----------------
// Rationale: LDS-pipe ledger showed reads were the binding resource at wave-tile
// 128x64 (0.375 b128/MFMA -> 147k cyc/CU > MFMA 159k... + writes = 211k = 88us floor).
// Wave-tile 128x128 cuts reads/MFMA to 0.25: reads 98k + writes 64k = 162k ~ MFMA.
// Cost: acc f32x4[8][8] = 256 AGPR -> 1 wave/SIMD; launch_bounds(256,1) unlocks the
// 512-reg budget (no spill through ~450, m08). Latency hiding is ILP within the
// single 2-barrier scheduling region (compiler's counted lgkmcnt waits, m97 asm).
// 16x16x32 MFMA (conflict-free frag pattern at 128-B rows; 32x32 falsified in r9).
// Dataflow (r6-verified): A(t+1)->other buf at tile top; B(t+2)->current buf after
// B2 (all frag reads complete); counted vmcnt(8) fence + B1 at tile end.

__global__ __launch_bounds__(256, 1) void gemm_lstm(
        const unsigned short* __restrict__ A,
        const unsigned short* __restrict__ Bt,
        const float* __restrict__ bias,
        const float* __restrict__ cprev,
        float* __restrict__ out) {
    __shared__ unsigned short lds[65536];          // 128 KiB
#define ASB(b) (lds + (b) * 16384)
#define BSB(b) (lds + 32768 + (b) * 16384)

    const int tid  = threadIdx.x;
    const int wid  = tid >> 6;                     // 0..3
    const int lane = tid & 63;
    const int wm = wid >> 1, wn = wid & 1;         // 2M x 2N wave grid
    const int lr = lane & 15, lq = lane >> 4;
    const int bm = blockIdx.y, bc = blockIdx.x;

    // staging geometry: half-tile = 128 rows x 64 cols = 16 KB; 4 waves x 1 KB x 4 passes
    const int X0 = wid * 1024 + lane * 16;                 // bytes, [0,4096) = rows 0..31
    const int rs = X0 >> 7;
    const int cs = ((X0 & 127) ^ ((rs & 7) << 4)) >> 1;    // element col (pre-swizzled src)
    const unsigned short* Agb = A  + ((size_t)(bm * 256 + rs)) * 4096 + cs;
    const unsigned short* Bgb = Bt + ((size_t)(bc * 256 + rs)) * 4096 + cs;

    // ds_read fragment col offsets (elements), read-side swizzle (row&7)<<4 on bytes
    const int swz = (lr & 7) << 4;
    const int ca0 = ((lq * 16) ^ swz) >> 1;        // ks=0
    const int ca1 = ((64 + lq * 16) ^ swz) >> 1;   // ks=1

    f32x4 acc[8][8] = {};                          // acc[mi][ni], ni = hi*4 + gate

    // one STAGE = one half-tile (128 rows x 64 cols): 4 gl2lds/wave, pass j adds
    // 32 rows (rs&7 invariant -> cs constant) and 4096 B of LDS.
#define STAGE_A(b, h, kt) do {                                               \
        unsigned short* _d = ASB(b) + (h) * 8192 + wid * 512;                \
        const unsigned short* _s = Agb + (size_t)((h) * 128) * 4096 + (kt) * 64; \
        gl2lds16(_s,                 _d);                                    \
        gl2lds16(_s + 32 * 4096,     _d + 2048);                             \
        gl2lds16(_s + 64 * 4096,     _d + 4096);                             \
        gl2lds16(_s + 96 * 4096,     _d + 6144);                             \
    } while (0)
#define STAGE_B(b, h, kt) do {                                               \
        unsigned short* _d = BSB(b) + (h) * 8192 + wid * 512;                \
        const unsigned short* _s = Bgb + (size_t)((h) * 128) * 4096 + (kt) * 64; \
        gl2lds16(_s,                 _d);                                    \
        gl2lds16(_s + 32 * 4096,     _d + 2048);                             \
        gl2lds16(_s + 64 * 4096,     _d + 4096);                             \
        gl2lds16(_s + 96 * 4096,     _d + 6144);                             \
    } while (0)
#define LDA(buf, mi, cax) (*reinterpret_cast<const bf16x8*>((buf) + (wm * 128 + (mi) * 16 + lr) * 64 + (cax)))
#define LDB(buf, ni, cax) (*reinterpret_cast<const bf16x8*>((buf) + (wn * 128 + (ni) * 16 + lr) * 64 + (cax)))
#define SBAR() __builtin_amdgcn_s_barrier()
#define VMFENCE() asm volatile("s_waitcnt vmcnt(8)" ::: "memory")

#define KITER(T, PAR) do {                                                   \
        const unsigned short* Ac = ASB(PAR);                                 \
        const unsigned short* Bc = BSB(PAR);                                 \
        const int ktA = ((T) < 63) ? (T) + 1 : 63;                           \
        const int ktB = ((T) < 62) ? (T) + 2 : 63;                           \
        STAGE_A(PAR ^ 1, 0, ktA);                                            \
        STAGE_A(PAR ^ 1, 1, ktA);                                            \
        _Pragma("unroll")                                                    \
        for (int ks = 0; ks < 2; ++ks) {                                     \
            const int cax = ks ? ca1 : ca0;                                  \
            bf16x8 af[8], bfr[8];                                            \
            _Pragma("unroll")                                                \
            for (int m = 0; m < 8; ++m)  af[m]  = LDA(Ac, m, cax);           \
            _Pragma("unroll")                                                \
            for (int n = 0; n < 8; ++n)  bfr[n] = LDB(Bc, n, cax);           \
            __builtin_amdgcn_s_setprio(1);                                   \
            _Pragma("unroll")                                                \
            for (int m = 0; m < 8; ++m)                                      \
            _Pragma("unroll")                                                \
            for (int n = 0; n < 8; ++n)                                      \
                acc[m][n] = __builtin_amdgcn_mfma_f32_16x16x32_bf16(         \
                    af[m], bfr[n], acc[m][n], 0, 0, 0);                      \
            __builtin_amdgcn_s_setprio(0);                                   \
        }                                                                    \
        asm volatile("s_waitcnt lgkmcnt(0)");                                \
        SBAR();   /* B2: all frag reads complete -> B region writable */     \
        STAGE_B(PAR, 0, ktB);                                                \
        STAGE_B(PAR, 1, ktB);                                                \
        VMFENCE();                                                           \
        SBAR();   /* B1: tile T+1 staged data ready */                       \
    } while (0)

    // ---- prologue: tile0 A+B, tile1 B staged (24 loads) ----
    STAGE_A(0, 0, 0); STAGE_A(0, 1, 0);
    STAGE_B(0, 0, 0); STAGE_B(0, 1, 0);
    STAGE_B(1, 0, 1); STAGE_B(1, 1, 1);
    VMFENCE();                                     // drains tile0's 16 loads
    SBAR();

    for (int u = 0; u < 32; ++u) {
        KITER(2 * u, 0);
        KITER(2 * u + 1, 1);
    }

    // ---- fused LSTM epilogue ----
    // lane lr of wave wn holds gates a,i,f,o of unit u0 (ni=0..3) and u0+16 (ni=4..7)
    const int u0 = bc * 64 + wn * 32 + lr;
    float* outh = out;
    float* outc = out + (size_t)4096 * 1024;

#pragma unroll
    for (int hi = 0; hi < 2; ++hi) {
        const int un = u0 + hi * 16;
        const float ba  = bias[un];
        const float bi  = bias[1024 + un];
        const float bfv = bias[2048 + un];
        const float bo  = bias[3072 + un];
#pragma unroll
        for (int mi = 0; mi < 8; ++mi) {
            const int r0 = bm * 256 + wm * 128 + mi * 16 + lq * 4;
#pragma unroll
            for (int r = 0; r < 4; ++r) {
                const size_t off = (size_t)(r0 + r) * 1024 + un;
                const float a  = acc[mi][hi * 4 + 0][r] + ba;
                const float ii = acc[mi][hi * 4 + 1][r] + bi;
                const float ff = acc[mi][hi * 4 + 2][r] + bfv;
                const float oo = acc[mi][hi * 4 + 3][r] + bo;
                const float c  = tanh_fast(a) * sigf(ii) + sigf(ff) * cprev[off];
                outh[off] = sigf(oo) * tanh_fast(c);
                outc[off] = c;
            }
        }
    }
#undef STAGE_A
#undef STAGE_B
#undef LDA
#undef LDB
#undef SBAR
#undef VMFENCE
#undef KITER
#undef ASB
#undef BSB
}

// ---------------- launch ----------------

extern "C" void kernel_launch(void* const* d_in, const int* in_sizes, int n_in,
                              void* d_out, int out_size, void* d_ws, size_t ws_size,
                              hipStream_t stream) {
    const float* top_buf = (const float*)d_in[0];
    const float* s1      = (const float*)d_in[1];
    const float* s2      = (const float*)d_in[2];
    const float* hprev   = (const float*)d_in[3];
    const float* cprev   = (const float*)d_in[4];
    const float* Wb      = (const float*)d_in[5];
    const float* W1      = (const float*)d_in[6];
    const float* W2      = (const float*)d_in[7];
    const float* Wl      = (const float*)d_in[8];
    const float* bl      = (const float*)d_in[9];

    unsigned short* Abf = (unsigned short*)d_ws;                 // 32 MB
    unsigned short* Bt  = Abf + (size_t)4096 * 4096;             // 32 MB

    convert_AB<<<32768, 256, 0, stream>>>(top_buf, s1, s2, hprev,
                                          Wb, W1, W2, Wl, Abf, Bt);

    dim3 grid(16, 16);
    gemm_lstm<<<grid, 256, 0, stream>>>(Abf, Bt, bl, cprev, (float*)d_out);
}